// Round 9
// baseline (96.095 us; speedup 1.0000x reference)
//
#include <hip/hip_runtime.h>
#include <hip/hip_bf16.h>

// QuantumKANLayer: S = [cos|sin features](32768x4096) @ W(4096x256), bf16 MFMA.
// R8: counted-vmcnt deep pipeline (T3+T4) on the validated R7 building blocks.
//   - BM=128 x BN=256, grid 256 (1 block/CU), 8 waves = 2M x 4N, wave 64x64.
//   - B triple-buffered in LDS, DMA'd 2 tiles ahead via global_load_lds.
//   - Exactly 5 VMEM ops per tile region (1 x-load + 4 gload_lds);
//     per-tile barrier = s_waitcnt vmcnt(5) lgkmcnt(0) + raw s_barrier.
//     NO __syncthreads in the loop -> no vmcnt(0) drain (the m97 ceiling).
//   - A generated in-lane (Chebyshev chains), double-buffered (t+1 during t).
//
// k-slot semantics: slice = one input column i; slot h*8+e <->
// (h ? sin : cos)((e+1) * x[row][i]).   i = t*4 + s,  t = 0..63.

#define NT 64            // K-tiles; each = 4 slices x 16 k = 64 k

typedef __attribute__((ext_vector_type(8)))  short short8;
typedef __attribute__((ext_vector_type(16))) float f32x16;

typedef __attribute__((address_space(3))) void lds_void;
typedef const __attribute__((address_space(1))) void gbl_void;

static __device__ __forceinline__ unsigned short f2bf(float f) {
    union { float f; unsigned u; } v; v.f = f;
    unsigned r = v.u + 0x7fff + ((v.u >> 16) & 1);   // RNE
    return (unsigned short)(r >> 16);
}

// ---- pack W^T fragment-major for 32x32x16 B-frags -------------------------
// granule (i, cg) at wt + ((i*8+cg)*64+l)*8 shorts; lane l (16B):
// col j = cg*32 + (l&31), h = l>>5, val[e] = (h ? coef_b : coef_a)[j][i][e]
__global__ __launch_bounds__(256) void pack_w_kernel(
        const float* __restrict__ ca, const float* __restrict__ cb,
        unsigned short* __restrict__ wt) {
    int idx = blockIdx.x * 256 + threadIdx.x;   // 131072
    int l  = idx & 63;
    int cg = (idx >> 6) & 7;
    int i  = idx >> 9;
    int j  = cg * 32 + (l & 31);
    const float* src = ((l >> 5) ? cb : ca) + ((size_t)j * 256 + i) * 8;
    float4 v0 = ((const float4*)src)[0];
    float4 v1 = ((const float4*)src)[1];
    alignas(16) unsigned short o[8];
    o[0] = f2bf(v0.x); o[1] = f2bf(v0.y); o[2] = f2bf(v0.z); o[3] = f2bf(v0.w);
    o[4] = f2bf(v1.x); o[5] = f2bf(v1.y); o[6] = f2bf(v1.z); o[7] = f2bf(v1.w);
    *(short8*)(wt + (size_t)idx * 8) = *(short8*)o;
}

// ---- fused feature-gen + GEMM --------------------------------------------
template<bool PACKED>
__global__ __launch_bounds__(512, 2) void kan_gemm(
        const float* __restrict__ x,
        const unsigned short* __restrict__ bwt,
        const float* __restrict__ ca, const float* __restrict__ cb,
        float* __restrict__ out) {
    // A: [buf][slice*2+h][row][16B] = 2 x 16 KB. B: 3 x 32 KB. Total 128 KB.
    __shared__ __align__(16) char Alds[2][8][128][16];
    __shared__ __align__(16) char Blds[3][32768];

    const int tid   = threadIdx.x;
    const int l     = tid & 63;
    const int w     = tid >> 6;       // 0..7
    const int lrow  = l & 31;
    const int lhalf = l >> 5;
    const int wm    = w & 1;          // 2 M-waves
    const int wn    = w >> 1;         // 4 N-waves
    const int bm0   = blockIdx.x * 128;

    // chain task: one (row, i-subcolumn) pair per thread
    const int crow = tid >> 2;        // 0..127
    const int cii  = tid & 3;         // 0..3
    const float* xq = x + (size_t)(bm0 + crow) * 256 + cii;

    f32x16 acc[2][2];
#pragma unroll
    for (int m = 0; m < 2; ++m)
#pragma unroll
        for (int n = 0; n < 2; ++n)
#pragma unroll
            for (int r = 0; r < 16; ++r) acc[m][n][r] = 0.0f;

    auto stageB = [&](int dbuf, int tt) {
        if (PACKED) {
            const char* src = (const char*)bwt + (size_t)tt * 32768;
            char* dst = &Blds[dbuf][0];
#pragma unroll
            for (int p = 0; p < 4; ++p) {
                const int go = p * 512 + w * 64;          // wave-uniform
                __builtin_amdgcn_global_load_lds(
                    (gbl_void*)(src + (size_t)(go + l) * 16),
                    (lds_void*)(dst + (size_t)go * 16), 16, 0, 0);
            }
        } else {
            // thread granule p: slice s=p, cg=w, lane l
#pragma unroll
            for (int p = 0; p < 4; ++p) {
                const int i = tt * 4 + p;
                const int j = w * 32 + lrow;
                const float* s = (lhalf ? cb : ca) + ((size_t)j * 256 + i) * 8;
                float4 v0 = ((const float4*)s)[0];
                float4 v1 = ((const float4*)s)[1];
                alignas(16) unsigned short o[8];
                o[0] = f2bf(v0.x); o[1] = f2bf(v0.y);
                o[2] = f2bf(v0.z); o[3] = f2bf(v0.w);
                o[4] = f2bf(v1.x); o[5] = f2bf(v1.y);
                o[6] = f2bf(v1.z); o[7] = f2bf(v1.w);
                *(short8*)(&Blds[dbuf][0] + (size_t)(p * 512 + w * 64 + l) * 16)
                    = *(short8*)o;
            }
        }
    };

    // 8 cos + 8 sin harmonics for (crow, i): two Chebyshev chains, 2 ds_writes
    auto chains = [&](int abuf, float xv) {
        float s1, c1;
        __sincosf(xv, &s1, &c1);
        alignas(16) __hip_bfloat16 fc[8], fs[8];
        fc[0] = __float2bfloat16(c1); fs[0] = __float2bfloat16(s1);
        const float tc = c1 + c1;
        float cp2 = 1.0f, cp1 = c1, sp2 = 0.0f, sp1 = s1;
#pragma unroll
        for (int k = 1; k < 8; ++k) {
            const float cn = __builtin_fmaf(tc, cp1, -cp2);
            const float sn = __builtin_fmaf(tc, sp1, -sp2);
            cp2 = cp1; cp1 = cn; sp2 = sp1; sp1 = sn;
            fc[k] = __float2bfloat16(cn); fs[k] = __float2bfloat16(sn);
        }
        *(short8*)(&Alds[abuf][cii * 2 + 0][crow][0]) = *(short8*)fc;
        *(short8*)(&Alds[abuf][cii * 2 + 1][crow][0]) = *(short8*)fs;
    };

    // ---- prologue: regions for virtual tiles -2, -1 ------------------------
    float xcur  = xq[0];              // x(0) for chains(0)
    float xnext = xq[4];              // x(1), consumed at t=0
    stageB(0, 0);
    float xnn   = xq[8];              // x(2), consumed at t=1
    stageB(1, 1);
    chains(0, xcur);                  // A(0)

    int rb = 0;                       // t % 3 (B read buffer)
#pragma unroll 1
    for (int t = 0; t < NT; ++t) {
        // tile barrier: keep the 5 newest VMEM ops (region t-1) in flight
        __builtin_amdgcn_sched_barrier(0);
        asm volatile("s_waitcnt vmcnt(5) lgkmcnt(0)" ::: "memory");
        __builtin_amdgcn_s_barrier();
        __builtin_amdgcn_sched_barrier(0);

        const int tp2 = (t + 2 < NT) ? t + 2 : NT - 1;
        const int tp3 = (t + 3 < NT) ? t + 3 : NT - 1;
        const int sbuf = (rb + 2 >= 3) ? (rb - 1) : (rb + 2);   // (t+2)%3

        const float xf = xq[(size_t)tp3 * 4];   // 1 VMEM
        stageB(sbuf, tp2);                      // 4 VMEM

        chains((t + 1) & 1, xnext);             // A(t+1), lgkm only

        const char* Ab = &Alds[t & 1][0][0][0];
        const char* Bb = &Blds[rb][0];
#pragma unroll
        for (int s = 0; s < 4; ++s) {
            const short8 a0 = *(const short8*)(
                Ab + (size_t)((s * 2 + lhalf) * 128 + wm * 64 + lrow) * 16);
            const short8 a1 = *(const short8*)(
                Ab + (size_t)((s * 2 + lhalf) * 128 + wm * 64 + 32 + lrow) * 16);
            const short8 b0 = *(const short8*)(
                Bb + (size_t)((s * 8 + wn * 2) * 64 + l) * 16);
            const short8 b1 = *(const short8*)(
                Bb + (size_t)((s * 8 + wn * 2 + 1) * 64 + l) * 16);
            __builtin_amdgcn_s_setprio(1);
            acc[0][0] = __builtin_amdgcn_mfma_f32_32x32x16_bf16(
                a0, b0, acc[0][0], 0, 0, 0);
            acc[0][1] = __builtin_amdgcn_mfma_f32_32x32x16_bf16(
                a0, b1, acc[0][1], 0, 0, 0);
            acc[1][0] = __builtin_amdgcn_mfma_f32_32x32x16_bf16(
                a1, b0, acc[1][0], 0, 0, 0);
            acc[1][1] = __builtin_amdgcn_mfma_f32_32x32x16_bf16(
                a1, b1, acc[1][1], 0, 0, 0);
            __builtin_amdgcn_s_setprio(0);
        }

        xnext = xnn; xnn = xf;
        rb = (rb + 1 == 3) ? 0 : rb + 1;
    }

    // ---- epilogue: 32x32 C/D: col = lane&31, row = (r&3)+8*(r>>2)+4*lhalf --
#pragma unroll
    for (int m = 0; m < 2; ++m)
#pragma unroll
        for (int n = 0; n < 2; ++n) {
            const int ocol = wn * 64 + n * 32 + lrow;
#pragma unroll
            for (int r = 0; r < 16; ++r) {
                const int orow = bm0 + wm * 64 + m * 32
                               + (r & 3) + 8 * (r >> 2) + 4 * lhalf;
                out[(size_t)orow * 256 + ocol] = acc[m][n][r];
            }
        }
}

extern "C" void kernel_launch(void* const* d_in, const int* in_sizes, int n_in,
                              void* d_out, int out_size, void* d_ws, size_t ws_size,
                              hipStream_t stream) {
    const float* x  = (const float*)d_in[0];
    const float* ca = (const float*)d_in[1];
    const float* cb = (const float*)d_in[2];
    float* out = (float*)d_out;

    const size_t wt_bytes = (size_t)131072 * 16;   // 2 MiB

    if (ws_size >= wt_bytes) {
        unsigned short* wt = (unsigned short*)d_ws;
        pack_w_kernel<<<512, 256, 0, stream>>>(ca, cb, wt);
        kan_gemm<true><<<256, 512, 0, stream>>>(x, wt, ca, cb, out);
    } else {
        kan_gemm<false><<<256, 512, 0, stream>>>(x, nullptr, ca, cb, out);
    }
}

// Round 10
// 95.510 us; speedup vs baseline: 1.0061x; 1.0061x over previous
//
#include <hip/hip_runtime.h>
#include <hip/hip_bf16.h>

// QuantumKANLayer: S = [cos|sin features](32768x4096) @ W(4096x256), bf16 MFMA.
// R9 = R8 pipeline (3-deep B via global_load_lds, counted vmcnt, raw s_barrier)
//      + conflict-free A-write mapping (crow=tid&127: 8-lane-contiguous
//        ds_write_b128 stripes)  [R8 had 6.4M conflict cycles]
//      + 2 blocks/CU: BN=128 column split, grid 512, LDS 80KB/block
//        (A 2x16KB dbuf + B 3x16KB), 16 waves/CU TLP.
//
// k-slot semantics: slice = input column i; slot h*8+e <->
// (h ? sin : cos)((e+1) * x[row][i]).   i = t*4 + s,  t = 0..63.

#define NT 64            // K-tiles; each = 4 slices x 16 k = 64 k

typedef __attribute__((ext_vector_type(8)))  short short8;
typedef __attribute__((ext_vector_type(16))) float f32x16;

typedef __attribute__((address_space(3))) void lds_void;
typedef const __attribute__((address_space(1))) void gbl_void;

static __device__ __forceinline__ unsigned short f2bf(float f) {
    union { float f; unsigned u; } v; v.f = f;
    unsigned r = v.u + 0x7fff + ((v.u >> 16) & 1);   // RNE
    return (unsigned short)(r >> 16);
}

// ---- pack W^T fragment-major for 32x32x16 B-frags -------------------------
// granule (i, cg) at wt + ((i*8+cg)*64+l)*8 shorts; lane l (16B):
// col j = cg*32 + (l&31), h = l>>5, val[e] = (h ? coef_b : coef_a)[j][i][e]
__global__ __launch_bounds__(256) void pack_w_kernel(
        const float* __restrict__ ca, const float* __restrict__ cb,
        unsigned short* __restrict__ wt) {
    int idx = blockIdx.x * 256 + threadIdx.x;   // 131072
    int l  = idx & 63;
    int cg = (idx >> 6) & 7;
    int i  = idx >> 9;
    int j  = cg * 32 + (l & 31);
    const float* src = ((l >> 5) ? cb : ca) + ((size_t)j * 256 + i) * 8;
    float4 v0 = ((const float4*)src)[0];
    float4 v1 = ((const float4*)src)[1];
    alignas(16) unsigned short o[8];
    o[0] = f2bf(v0.x); o[1] = f2bf(v0.y); o[2] = f2bf(v0.z); o[3] = f2bf(v0.w);
    o[4] = f2bf(v1.x); o[5] = f2bf(v1.y); o[6] = f2bf(v1.z); o[7] = f2bf(v1.w);
    *(short8*)(wt + (size_t)idx * 8) = *(short8*)o;
}

// ---- fused feature-gen + GEMM --------------------------------------------
// grid 512 = 256 rb x 2 ch. Block: rows rb*128..+127, cols ch*128..+127.
// 8 waves = 2M x 4N; wave = 64 rows x 32 cols (acc[2][1]).
template<bool PACKED>
__global__ __launch_bounds__(512, 4) void kan_gemm(
        const float* __restrict__ x,
        const unsigned short* __restrict__ bwt,
        const float* __restrict__ ca, const float* __restrict__ cb,
        float* __restrict__ out) {
    // A: [buf][slice*2+h][row][16B] = 2 x 16 KB. B: 3 x 16 KB. Total 80 KB.
    __shared__ __align__(16) char Alds[2][8][128][16];
    __shared__ __align__(16) char Blds[3][16384];

    const int tid   = threadIdx.x;
    const int l     = tid & 63;
    const int w     = tid >> 6;       // 0..7
    const int lrow  = l & 31;
    const int lhalf = l >> 5;
    const int wm    = w & 1;          // 2 M-waves
    const int wn    = w >> 1;         // 4 N-waves
    const int rb    = blockIdx.x >> 1;
    const int ch    = blockIdx.x & 1;
    const int bm0   = rb * 128;

    // chain task: conflict-free mapping — 8-lane-contiguous rows
    const int crow = tid & 127;       // row 0..127
    const int cii  = tid >> 7;        // slice-in-tile 0..3
    const float* xq = x + (size_t)(bm0 + crow) * 256 + cii;

    f32x16 acc[2];
#pragma unroll
    for (int m = 0; m < 2; ++m)
#pragma unroll
        for (int r = 0; r < 16; ++r) acc[m][r] = 0.0f;

    auto stageB = [&](int dbuf, int tt) {
        // 1024 granules of 16B; wave w covers granules {w*64.., 512+w*64..}
#pragma unroll
        for (int p = 0; p < 2; ++p) {
            const int go = p * 512 + w * 64;            // wave-uniform base
            const int G  = (go + l) >> 6;               // granule group 0..15
            const int s  = G >> 2;                      // slice in tile
            const int cgl = G & 3;                      // local col-group
            if (PACKED) {
                const char* src = (const char*)bwt
                    + ((size_t)(((tt * 4 + s) * 8 + ch * 4 + cgl) * 64 + l)) * 16;
                char* dst = &Blds[dbuf][0] + (size_t)go * 16;
                __builtin_amdgcn_global_load_lds((gbl_void*)src, (lds_void*)dst,
                                                 16, 0, 0);
            } else {
                const int j = (ch * 4 + cgl) * 32 + lrow;
                const int i = tt * 4 + s;
                const float* sp = (lhalf ? cb : ca) + ((size_t)j * 256 + i) * 8;
                float4 v0 = ((const float4*)sp)[0];
                float4 v1 = ((const float4*)sp)[1];
                alignas(16) unsigned short o[8];
                o[0] = f2bf(v0.x); o[1] = f2bf(v0.y);
                o[2] = f2bf(v0.z); o[3] = f2bf(v0.w);
                o[4] = f2bf(v1.x); o[5] = f2bf(v1.y);
                o[6] = f2bf(v1.z); o[7] = f2bf(v1.w);
                *(short8*)(&Blds[dbuf][0] + (size_t)(go + l) * 16) = *(short8*)o;
            }
        }
    };

    // 8 cos + 8 sin harmonics for (crow, i): two Chebyshev chains, 2 ds_writes
    auto chains = [&](int abuf, float xv) {
        float s1, c1;
        __sincosf(xv, &s1, &c1);
        alignas(16) __hip_bfloat16 fc[8], fs[8];
        fc[0] = __float2bfloat16(c1); fs[0] = __float2bfloat16(s1);
        const float tc = c1 + c1;
        float cp2 = 1.0f, cp1 = c1, sp2 = 0.0f, sp1 = s1;
#pragma unroll
        for (int k = 1; k < 8; ++k) {
            const float cn = __builtin_fmaf(tc, cp1, -cp2);
            const float sn = __builtin_fmaf(tc, sp1, -sp2);
            cp2 = cp1; cp1 = cn; sp2 = sp1; sp1 = sn;
            fc[k] = __float2bfloat16(cn); fs[k] = __float2bfloat16(sn);
        }
        *(short8*)(&Alds[abuf][cii * 2 + 0][crow][0]) = *(short8*)fc;
        *(short8*)(&Alds[abuf][cii * 2 + 1][crow][0]) = *(short8*)fs;
    };

    // ---- prologue ----------------------------------------------------------
    float xcur  = xq[0];
    float xnext = xq[4];
    stageB(0, 0);
    float xnn   = xq[8];
    stageB(1, 1);
    chains(0, xcur);

    int rb3 = 0;                      // t % 3 (B read buffer)
#pragma unroll 1
    for (int t = 0; t < NT; ++t) {
        // keep the newest 3 VMEM ops (this-region prefetches not yet issued;
        // previous region's 3) in flight; drain region t-2 -> B(t) ready
        __builtin_amdgcn_sched_barrier(0);
        asm volatile("s_waitcnt vmcnt(3) lgkmcnt(0)" ::: "memory");
        __builtin_amdgcn_s_barrier();
        __builtin_amdgcn_sched_barrier(0);

        const int tp2 = (t + 2 < NT) ? t + 2 : NT - 1;
        const int tp3 = (t + 3 < NT) ? t + 3 : NT - 1;
        const int sbuf = (rb3 + 2 >= 3) ? (rb3 - 1) : (rb3 + 2);   // (t+2)%3

        const float xf = xq[(size_t)tp3 * 4];   // 1 VMEM
        stageB(sbuf, tp2);                      // 2 VMEM

        chains((t + 1) & 1, xnext);             // A(t+1): VALU + ds_write only

        const char* Ab = &Alds[t & 1][0][0][0];
        const char* Bb = &Blds[rb3][0];
#pragma unroll
        for (int s = 0; s < 4; ++s) {
            const short8 a0 = *(const short8*)(
                Ab + (size_t)((s * 2 + lhalf) * 128 + wm * 64 + lrow) * 16);
            const short8 a1 = *(const short8*)(
                Ab + (size_t)((s * 2 + lhalf) * 128 + wm * 64 + 32 + lrow) * 16);
            const short8 b0 = *(const short8*)(
                Bb + (size_t)((s * 4 + wn) * 64 + l) * 16);
            __builtin_amdgcn_s_setprio(1);
            acc[0] = __builtin_amdgcn_mfma_f32_32x32x16_bf16(
                a0, b0, acc[0], 0, 0, 0);
            acc[1] = __builtin_amdgcn_mfma_f32_32x32x16_bf16(
                a1, b0, acc[1], 0, 0, 0);
            __builtin_amdgcn_s_setprio(0);
        }

        xnext = xnn; xnn = xf;
        rb3 = (rb3 + 1 == 3) ? 0 : rb3 + 1;
    }

    // ---- epilogue: 32x32 C/D: col = lane&31, row = (r&3)+8*(r>>2)+4*lhalf --
    const int ocol = ch * 128 + wn * 32 + lrow;
#pragma unroll
    for (int m = 0; m < 2; ++m)
#pragma unroll
        for (int r = 0; r < 16; ++r) {
            const int orow = bm0 + wm * 64 + m * 32
                           + (r & 3) + 8 * (r >> 2) + 4 * lhalf;
            out[(size_t)orow * 256 + ocol] = acc[m][r];
        }
}

extern "C" void kernel_launch(void* const* d_in, const int* in_sizes, int n_in,
                              void* d_out, int out_size, void* d_ws, size_t ws_size,
                              hipStream_t stream) {
    const float* x  = (const float*)d_in[0];
    const float* ca = (const float*)d_in[1];
    const float* cb = (const float*)d_in[2];
    float* out = (float*)d_out;

    const size_t wt_bytes = (size_t)131072 * 16;   // 2 MiB

    if (ws_size >= wt_bytes) {
        unsigned short* wt = (unsigned short*)d_ws;
        pack_w_kernel<<<512, 256, 0, stream>>>(ca, cb, wt);
        kan_gemm<true><<<512, 512, 0, stream>>>(x, wt, ca, cb, out);
    } else {
        kan_gemm<false><<<512, 512, 0, stream>>>(x, nullptr, ca, cb, out);
    }
}